// Round 1
// 165.828 us; speedup vs baseline: 1.0064x; 1.0064x over previous
//
#include <hip/hip_runtime.h>
#include <math.h>

#define B_   8
#define T_   12
#define BT   96      // B*T
#define N_   1000
#define FIN  64
#define H_   8
#define FOUT 16
#define HF   128     // H*FOUT
#define E_   8000

typedef unsigned short u16;
typedef unsigned int   u32;
typedef __attribute__((ext_vector_type(8))) short  short8;   // 8 bf16 (4 VGPR)
typedef __attribute__((ext_vector_type(4))) float  float4v;  // MFMA acc

__device__ __forceinline__ float bf2f(u16 u) {
    return __uint_as_float(((u32)u) << 16);
}
__device__ __forceinline__ void unpack2(u32 q, float& lo, float& hi) {
    lo = __uint_as_float(q << 16);
    hi = __uint_as_float(q & 0xffff0000u);
}
__device__ __forceinline__ u16 f2bf(float f) {
    u32 x = __float_as_uint(f);
    u32 r = (x + 0x7fffu + ((x >> 16) & 1u)) >> 16;   // RNE
    return (u16)r;
}
__device__ __forceinline__ u32 pack2bf(float lo, float hi) {
    return (u32)f2bf(lo) | ((u32)f2bf(hi) << 16);
}

// ---------------------------------------------------------------------------
// Workspace carve (float-element offsets) — same 55.4 MB footprint.
// sTs/sTt merged into one sT fp32 [n][bt][16] (cols 0-7 = aS, 8-15 = aT).
// ---------------------------------------------------------------------------
#define OFF_FLAGS   0         // 4 ints
#define OFF_OFFS    264       // 1004 ints
#define OFF_CSR     1268      // 8000 ints (stores src*BT, grouped by target)
#define OFF_WALL    9268      // W' bf16 [272][64] = 17408 u16 = 8704 floats
#define OFF_ST      17972     // 1536000 sT fp32 [n][bt][16]
#define OFF_PROJ    1553972   // projT bf16 [n][bt][128] = 12.288M u16
#define OFF_SKIP    7697972   // skipT bf16 [n][bt][128]

// ---------------------------------------------------------------------------
// K0 (prep, 1 block x 1024 thr): dtype probes -> flags; packed W' bf16
// [272][64] (proj | skip | aS | aT).  CSR build moved into k_mfma block 0.
// ---------------------------------------------------------------------------
__global__ __launch_bounds__(1024) void k_prep(const u32* __restrict__ xw,
                                               const u32* __restrict__ ew,
                                               const void* __restrict__ Wp,
                                               const void* __restrict__ Ws,
                                               const void* __restrict__ as_,
                                               const void* __restrict__ at_,
                                               int* __restrict__ flags,
                                               u16* __restrict__ Wall)
{
    __shared__ float WpL[HF * FIN];   // 32 KB canonical fp32 W_proj
    __shared__ int votes;
    __shared__ u32 orAcc;
    __shared__ int fB, fE;
    const int tid = threadIdx.x;

    if (tid == 0) { votes = 0; orAcc = 0u; }
    __syncthreads();

    if (tid < 256) {   // bf16-vs-fp32 probe on x
        const u32 w = xw[tid];
        const int e = (int)((w >> 7) & 0xFFu);
        if (e == 0 || (e >= 95 && e <= 140)) atomicAdd(&votes, 1);
    }
    {   // int64-vs-int32 probe on edge_index
        u32 o = 0;
        for (int i = 2 * tid + 1; i < 16000; i += 2048) o |= ew[i];
        atomicOr(&orAcc, o);
    }
    __syncthreads();
    if (tid == 0) {
        fB = (votes >= 160) ? 1 : 0;
        fE = (orAcc == 0u) ? 1 : 0;
        flags[0] = fB;
        flags[1] = fE;
    }
    __syncthreads();
    const bool bf = fB != 0;

    // canonical W -> LDS + packed bf16 W'
    for (int i = tid; i < HF * FIN; i += 1024) {
        const float wp = bf ? bf2f(((const u16*)Wp)[i]) : ((const float*)Wp)[i];
        const float wv = bf ? bf2f(((const u16*)Ws)[i]) : ((const float*)Ws)[i];
        WpL[i] = wp;
        Wall[i]            = f2bf(wp);
        Wall[HF * FIN + i] = f2bf(wv);
    }
    __syncthreads();

    // fold a through W_proj
    if (tid < H_ * FIN) {
        const int h = tid >> 6, k = tid & 63;
        float s1 = 0.f, s2 = 0.f;
#pragma unroll
        for (int f = 0; f < FOUT; f++) {
            const float w = WpL[(h * FOUT + f) * FIN + k];
            const float a1 = bf ? bf2f(((const u16*)as_)[h * FOUT + f])
                                : ((const float*)as_)[h * FOUT + f];
            const float a2 = bf ? bf2f(((const u16*)at_)[h * FOUT + f])
                                : ((const float*)at_)[h * FOUT + f];
            s1 = fmaf(a1, w, s1);
            s2 = fmaf(a2, w, s2);
        }
        Wall[256 * FIN + tid] = f2bf(s1);   // aS rows
        Wall[264 * FIN + tid] = f2bf(s2);   // aT rows
    }
}

// ---------------------------------------------------------------------------
// K1: MFMA GEMM  C[96000 x 272] = X[96000 x 64] . W'^T.
// Operands SWAPPED vs r6: mfma(Wfrag, Xfrag) -> lane (q,m) holds
// OUT[base+m][tile*16 + q*4 .. +3] => 4 consecutive output cols per lane
// => one dwordx2 (packed bf16) store per tile instead of 4 scalar u16
// stores (69 -> 17 store insts/lane, all dword-aligned).
// Block 0 builds the CSR (hidden under the GEMM); GEMM = blocks 1..1500.
// ---------------------------------------------------------------------------
__global__ __launch_bounds__(256) void k_mfma(const void* __restrict__ xin,
                                              const u16* __restrict__ Wall,
                                              const int* __restrict__ flags,
                                              const u32* __restrict__ ew,
                                              u16* __restrict__ projT,
                                              u16* __restrict__ skipT,
                                              float* __restrict__ sT,
                                              int* __restrict__ offs,
                                              int* __restrict__ csrS)
{
    __shared__ int cnt[1000];
    __shared__ int cur[1000];
    __shared__ int sc[256];

    const int tid = threadIdx.x;

    if (blockIdx.x == 0) {
        // ---- CSR build (256 thr, 1 block, overlapped with GEMM blocks) ----
        const bool i64 = flags[1] != 0;
        for (int i = tid; i < N_; i += 256) cnt[i] = 0;
        __syncthreads();
        for (int e = tid; e < E_; e += 256) {
            const int t = i64 ? (int)ew[2 * (E_ + e)] : (int)ew[E_ + e];
            atomicAdd(&cnt[t], 1);
        }
        __syncthreads();
        // blocked exclusive scan: thread t owns idx 4t..4t+3 (t < 250)
        int s0 = 0, s1 = 0, s2 = 0, s3 = 0, tot = 0;
        if (tid < 250) {
            s0 = cnt[4 * tid];
            s1 = cnt[4 * tid + 1];
            s2 = cnt[4 * tid + 2];
            s3 = cnt[4 * tid + 3];
            tot = s0 + s1 + s2 + s3;
        }
        sc[tid] = tot;
        __syncthreads();
        for (int d = 1; d < 256; d <<= 1) {
            int v = (tid >= d) ? sc[tid - d] : 0;
            __syncthreads();
            sc[tid] += v;
            __syncthreads();
        }
        int excl = (tid ? sc[tid - 1] : 0);
        if (tid < 250) {
            const int b = 4 * tid;
            offs[b]     = excl;
            offs[b + 1] = excl + s0;
            offs[b + 2] = excl + s0 + s1;
            offs[b + 3] = excl + s0 + s1 + s2;
            cur[b]     = excl;
            cur[b + 1] = excl + s0;
            cur[b + 2] = excl + s0 + s1;
            cur[b + 3] = excl + s0 + s1 + s2;
        }
        if (tid == 0) offs[N_] = E_;
        __syncthreads();
        for (int e = tid; e < E_; e += 256) {
            const int s = i64 ? (int)ew[2 * e] : (int)ew[e];
            const int t = i64 ? (int)ew[2 * (E_ + e)] : (int)ew[E_ + e];
            const int pos = atomicAdd(&cur[t], 1);
            csrS[pos] = s * BT;              // pre-scaled for k_att
        }
        return;
    }

    // ---- GEMM path (blocks 1..1500) ----
    const int wid  = tid >> 6;
    const int lid  = tid & 63;
    const int m    = lid & 15;
    const int q    = lid >> 4;
    const int base = (blockIdx.x - 1) * 64 + wid * 16;

    short8 x0, x1;   // X fragment (B-operand after swap)
    {
        const size_t xoff = (size_t)(base + m) * FIN + q * 8;
        if (flags[0]) {
            const u16* xp = (const u16*)xin + xoff;
            x0 = *reinterpret_cast<const short8*>(xp);
            x1 = *reinterpret_cast<const short8*>(xp + 32);
        } else {
            const float* xp = (const float*)xin + xoff;
            union { short8 v; u16 e[8]; } p0, p1;
#pragma unroll
            for (int i = 0; i < 8; i++) {
                p0.e[i] = f2bf(xp[i]);
                p1.e[i] = f2bf(xp[i + 32]);
            }
            x0 = p0.v;
            x1 = p1.v;
        }
    }

    // per-lane output row: row = bt*1000 + n  ->  ob = n*BT + bt
    const u32 rowm = (u32)(base + m);
    const u32 bt   = rowm / 1000u;
    const u32 n    = rowm - bt * 1000u;
    const u32 obm  = n * BT + bt;

    const short8* Wv = reinterpret_cast<const short8*>(Wall);
    u16* projBase = projT + (size_t)obm * HF;
    u16* skipBase = skipT + (size_t)obm * HF;

#pragma unroll
    for (int t = 0; t < 16; t++) {
        const int wr = t * 16 + m;
        const short8 b0 = Wv[wr * 8 + q];
        const short8 b1 = Wv[wr * 8 + q + 4];
        float4v acc = {0.f, 0.f, 0.f, 0.f};
        acc = __builtin_amdgcn_mfma_f32_16x16x32_bf16(b0, x0, acc, 0, 0, 0);
        acc = __builtin_amdgcn_mfma_f32_16x16x32_bf16(b1, x1, acc, 0, 0, 0);

        u16* dst = (t < 8) ? projBase : skipBase;
        const int col = ((t < 8) ? t : (t - 8)) * 16 + q * 4;
        uint2 v;
        v.x = pack2bf(acc[0], acc[1]);
        v.y = pack2bf(acc[2], acc[3]);
        *reinterpret_cast<uint2*>(dst + col) = v;          // 8B aligned store
    }

    {   // score tile: W' rows 256..271 -> sT cols 0..15 (aS | aT)
        const int wr = 256 + m;
        const short8 b0 = Wv[wr * 8 + q];
        const short8 b1 = Wv[wr * 8 + q + 4];
        float4v acc = {0.f, 0.f, 0.f, 0.f};
        acc = __builtin_amdgcn_mfma_f32_16x16x32_bf16(b0, x0, acc, 0, 0, 0);
        acc = __builtin_amdgcn_mfma_f32_16x16x32_bf16(b1, x1, acc, 0, 0, 0);
        *reinterpret_cast<float4v*>(sT + (size_t)obm * 16 + q * 4) = acc; // 16B
    }
}

// ---------------------------------------------------------------------------
// K2: attention gather, lane-specialized weights. grid (N_, 24), 256 thr.
// Wave -> bt = by*4 + wid. Lane j2: OUTPUT role owns cols 2*j2,2*j2+1
// (h_out = j2>>3); WEIGHT role computes exp for edge-slot (j2>>3), head
// (j2&7) -> 8x less exp/score work; consumers fetch via __shfl.
// No global-max subtraction: softmax is shift-invariant and scores are
// structurally bounded (|s| <~ 15 << 88), so exp cannot overflow.
// ---------------------------------------------------------------------------
__global__ __launch_bounds__(256) void k_att(const u16* __restrict__ projT,
                                             const u16* __restrict__ skipT,
                                             const float* __restrict__ sT,
                                             const int* __restrict__ offs,
                                             const int* __restrict__ csrS,
                                             const int* __restrict__ flags,
                                             void* __restrict__ out)
{
    const int n   = blockIdx.x;
    const int tid = threadIdx.x;
    const int bt  = blockIdx.y * 4 + (tid >> 6);
    const int j2  = tid & 63;
    const int hw  = j2 & 7;     // weight-role head
    const int ho  = j2 >> 3;    // output-role head / weight-role edge slot

    __shared__ int csrL[64];    // holds src*BT

    const float st_w   = sT[((size_t)n * BT + bt) * 16 + 8 + hw];
    const int   sboff  = bt * 16 + hw;          // score addr = csrL*16 + sboff
    const u32   oboff  = (u32)bt * HF + 2 * j2; // proj  addr = csrL*128 + oboff

    float y0 = 0.f, y1 = 0.f, den = 0.f;
    const int e0 = offs[n], e1 = offs[n + 1];

    for (int base = e0; base < e1; base += 64) {
        const int cnt = min(64, e1 - base);
        __syncthreads();
        if (tid < cnt) csrL[tid] = csrS[base + tid];
        __syncthreads();

        for (int i0 = 0; i0 < cnt; i0 += 8) {
            // weight role: one exp per lane
            const int eIdx = i0 + ho;
            const int sBTw = csrL[(eIdx < cnt) ? eIdx : 0];
            const float ss = sT[(size_t)sBTw * 16 + sboff];
            float sc = ss + st_w;
            sc = fmaxf(sc, 0.2f * sc);                  // leaky_relu(0.2)
            const float wm = (eIdx < cnt) ? __expf(sc) : 0.f;

            // accumulate 8 edges; weight for (edge k, head ho) from lane k*8+ho
#pragma unroll
            for (int k = 0; k < 8; k++) {
                const float wk = __shfl(wm, k * 8 + ho, 64);
                const int sBT = csrL[(i0 + k < cnt) ? (i0 + k) : 0];
                const u32 pq = *(const u32*)(projT + (size_t)sBT * HF + oboff);
                float lo, hi;
                unpack2(pq, lo, hi);
                den += wk;
                y0 = fmaf(wk, lo, y0);
                y1 = fmaf(wk, hi, y1);
            }
        }
    }

    const float rden = __builtin_amdgcn_rcpf(den + 1e-16f);
    float sk0, sk1;
    {
        const u32 sq = *(const u32*)(skipT + ((size_t)n * BT + bt) * HF + 2 * j2);
        unpack2(sq, sk0, sk1);
    }
    float o0 = fmaf(y0, rden, sk0);
    float o1 = fmaf(y1, rden, sk1);
    o0 = o0 > 0.f ? o0 : __expf(o0) - 1.0f;             // ELU (bf16-exact enough)
    o1 = o1 > 0.f ? o1 : __expf(o1) - 1.0f;

    const size_t ob = ((size_t)bt * N_ + n) * HF + 2 * j2;
    if (flags[0]) {
        ((u32*)out)[ob >> 1] = (u32)f2bf(o0) | ((u32)f2bf(o1) << 16);
    } else {
        *(float2*)((float*)out + ob) = make_float2(o0, o1);
    }
}

// ---------------------------------------------------------------------------
extern "C" void kernel_launch(void* const* d_in, const int* in_sizes, int n_in,
                              void* d_out, int out_size, void* d_ws, size_t ws_size,
                              hipStream_t stream)
{
    const void* x   = d_in[0];
    const u32*  ew  = (const u32*)d_in[1];
    const void* Wp  = d_in[2];
    const void* as_ = d_in[3];
    const void* at_ = d_in[4];
    const void* Ws  = d_in[5];

    float* ws    = (float*)d_ws;
    int*   flags = (int*)(ws + OFF_FLAGS);
    int*   offs  = (int*)(ws + OFF_OFFS);
    int*   csrS  = (int*)(ws + OFF_CSR);
    u16*   Wall  = (u16*)(ws + OFF_WALL);
    float* sT    = ws + OFF_ST;
    u16*   projT = (u16*)(ws + OFF_PROJ);
    u16*   skipT = (u16*)(ws + OFF_SKIP);

    k_prep<<<1, 1024, 0, stream>>>((const u32*)x, ew, Wp, Ws, as_, at_,
                                   flags, Wall);
    k_mfma<<<1501, 256, 0, stream>>>(x, Wall, flags, ew,
                                     projT, skipT, sT, offs, csrS);
    k_att <<<dim3(1000, 24), 256, 0, stream>>>(projT, skipT, sT,
                                               offs, csrS, flags, d_out);
}

// Round 2
// 149.231 us; speedup vs baseline: 1.1183x; 1.1112x over previous
//
#include <hip/hip_runtime.h>
#include <math.h>

#define B_   8
#define T_   12
#define BT   96      // B*T
#define N_   1000
#define FIN  64
#define H_   8
#define FOUT 16
#define HF   128     // H*FOUT
#define E_   8000

typedef unsigned short u16;
typedef unsigned int   u32;
typedef __attribute__((ext_vector_type(8))) short  short8;   // 8 bf16 (4 VGPR)
typedef __attribute__((ext_vector_type(4))) float  float4v;  // MFMA acc

__device__ __forceinline__ float bf2f(u16 u) {
    return __uint_as_float(((u32)u) << 16);
}
__device__ __forceinline__ void unpack2(u32 q, float& lo, float& hi) {
    lo = __uint_as_float(q << 16);
    hi = __uint_as_float(q & 0xffff0000u);
}
__device__ __forceinline__ u16 f2bf(float f) {
    u32 x = __float_as_uint(f);
    u32 r = (x + 0x7fffu + ((x >> 16) & 1u)) >> 16;   // RNE
    return (u16)r;
}
__device__ __forceinline__ u32 pack2bf(float lo, float hi) {
    return (u32)f2bf(lo) | ((u32)f2bf(hi) << 16);
}

// Fragment-permuted W' layout: element (row r, col c) of the 272x64 W' lives
// at index (((r>>4)*8 + (c>>5)*4 + ((c>>3)&3))*16 + (r&15))*8 + (c&7).
// => in k_mfma, tile t / lane (m,q) reads its two 16B MFMA fragments at LDS
// bytes  t*2048 + q*256 + m*16  and  t*2048 + 1024 + q*256 + m*16:
// a wave's 64 lanes cover 64 consecutive 16B chunks -> conflict-free.
__device__ __forceinline__ int wpos(int r, int c) {
    return (((r >> 4) * 8 + (c >> 5) * 4 + ((c >> 3) & 3)) * 16 + (r & 15)) * 8
           + (c & 7);
}

// ---------------------------------------------------------------------------
// Workspace carve (float-element offsets) — same 55.4 MB footprint.
// ---------------------------------------------------------------------------
#define OFF_FLAGS   0         // 4 ints
#define OFF_OFFS    264       // 1004 ints
#define OFF_CSR     1268      // 8000 ints (stores src*BT, grouped by target)
#define OFF_WALL    9268      // W' bf16 [272][64] = 17408 u16 (permuted layout)
#define OFF_ST      17972     // 1536000 sT fp32 [n][bt][16]
#define OFF_PROJ    1553972   // projT bf16 [n][bt][128] = 12.288M u16
#define OFF_SKIP    7697972   // skipT bf16 [n][bt][128]

// ---------------------------------------------------------------------------
// K0 (prep, 1 block x 1024 thr): dtype probes -> flags; packed W' bf16 in the
// fragment-permuted layout (proj | skip | aS | aT).
// ---------------------------------------------------------------------------
__global__ __launch_bounds__(1024) void k_prep(const u32* __restrict__ xw,
                                               const u32* __restrict__ ew,
                                               const void* __restrict__ Wp,
                                               const void* __restrict__ Ws,
                                               const void* __restrict__ as_,
                                               const void* __restrict__ at_,
                                               int* __restrict__ flags,
                                               u16* __restrict__ Wall)
{
    __shared__ float WpL[HF * FIN];   // 32 KB canonical fp32 W_proj
    __shared__ int votes;
    __shared__ u32 orAcc;
    __shared__ int fB, fE;
    const int tid = threadIdx.x;

    if (tid == 0) { votes = 0; orAcc = 0u; }
    __syncthreads();

    if (tid < 256) {   // bf16-vs-fp32 probe on x
        const u32 w = xw[tid];
        const int e = (int)((w >> 7) & 0xFFu);
        if (e == 0 || (e >= 95 && e <= 140)) atomicAdd(&votes, 1);
    }
    {   // int64-vs-int32 probe on edge_index
        u32 o = 0;
        for (int i = 2 * tid + 1; i < 16000; i += 2048) o |= ew[i];
        atomicOr(&orAcc, o);
    }
    __syncthreads();
    if (tid == 0) {
        fB = (votes >= 160) ? 1 : 0;
        fE = (orAcc == 0u) ? 1 : 0;
        flags[0] = fB;
        flags[1] = fE;
    }
    __syncthreads();
    const bool bf = fB != 0;

    // canonical W -> LDS + packed bf16 W' (permuted layout)
    for (int i = tid; i < HF * FIN; i += 1024) {
        const int r = i >> 6, c = i & 63;
        const float wp = bf ? bf2f(((const u16*)Wp)[i]) : ((const float*)Wp)[i];
        const float wv = bf ? bf2f(((const u16*)Ws)[i]) : ((const float*)Ws)[i];
        WpL[i] = wp;
        Wall[wpos(r, c)]       = f2bf(wp);
        Wall[wpos(128 + r, c)] = f2bf(wv);
    }
    __syncthreads();

    // fold a through W_proj -> rows 256..263 (aS) and 264..271 (aT)
    if (tid < H_ * FIN) {
        const int h = tid >> 6, k = tid & 63;
        float s1 = 0.f, s2 = 0.f;
#pragma unroll
        for (int f = 0; f < FOUT; f++) {
            const float w = WpL[(h * FOUT + f) * FIN + k];
            const float a1 = bf ? bf2f(((const u16*)as_)[h * FOUT + f])
                                : ((const float*)as_)[h * FOUT + f];
            const float a2 = bf ? bf2f(((const u16*)at_)[h * FOUT + f])
                                : ((const float*)at_)[h * FOUT + f];
            s1 = fmaf(a1, w, s1);
            s2 = fmaf(a2, w, s2);
        }
        Wall[wpos(256 + h, k)] = f2bf(s1);
        Wall[wpos(264 + h, k)] = f2bf(s2);
    }
}

// ---------------------------------------------------------------------------
// K1: MFMA GEMM  C[96000 x 272] = X[96000 x 64] . W'^T.
// 8 waves / 128 rows per block. W' (34 KB) is staged into LDS once per block;
// per-tile fragment reads are conflict-free ds_read_b128 (permuted layout),
// removing the 34 serialized global-load latencies per wave that made r1
// latency-bound (MfmaUtil 2.5%, VALUBusy 6.8%, occupancy 28%).
// Operands swapped: mfma(Wfrag, Xfrag) -> lane (q,m) holds 4 consecutive
// output cols of one row => one 8B packed-bf16 store per tile.
// Block 0 builds the CSR (hidden under the GEMM); GEMM = blocks 1..750.
// ---------------------------------------------------------------------------
__global__ __launch_bounds__(512) void k_mfma(const void* __restrict__ xin,
                                              const u16* __restrict__ Wall,
                                              const int* __restrict__ flags,
                                              const u32* __restrict__ ew,
                                              u16* __restrict__ projT,
                                              u16* __restrict__ skipT,
                                              float* __restrict__ sT,
                                              int* __restrict__ offs,
                                              int* __restrict__ csrS)
{
    __shared__ __align__(16) unsigned char smemRaw[34816];

    const int tid = threadIdx.x;

    if (blockIdx.x == 0) {
        // ---- CSR build (512 thr, 1 block, overlapped with GEMM blocks) ----
        int* cnt = (int*)smemRaw;          // [1000]
        int* cur = cnt + 1000;             // [1000]
        int* sc  = cur + 1000;             // [512]
        const bool i64 = flags[1] != 0;
        for (int i = tid; i < N_; i += 512) cnt[i] = 0;
        __syncthreads();
        for (int e = tid; e < E_; e += 512) {
            const int t = i64 ? (int)ew[2 * (E_ + e)] : (int)ew[E_ + e];
            atomicAdd(&cnt[t], 1);
        }
        __syncthreads();
        // blocked exclusive scan: thread t owns idx 2t, 2t+1 (t < 500)
        int s0 = 0, s1 = 0, tot = 0;
        if (tid < 500) {
            s0 = cnt[2 * tid];
            s1 = cnt[2 * tid + 1];
            tot = s0 + s1;
        }
        sc[tid] = tot;
        __syncthreads();
        for (int d = 1; d < 512; d <<= 1) {
            int v = (tid >= d) ? sc[tid - d] : 0;
            __syncthreads();
            sc[tid] += v;
            __syncthreads();
        }
        int excl = (tid ? sc[tid - 1] : 0);
        if (tid < 500) {
            offs[2 * tid]     = excl;
            offs[2 * tid + 1] = excl + s0;
            cur[2 * tid]      = excl;
            cur[2 * tid + 1]  = excl + s0;
        }
        if (tid == 0) offs[N_] = E_;
        __syncthreads();
        for (int e = tid; e < E_; e += 512) {
            const int s = i64 ? (int)ew[2 * e] : (int)ew[e];
            const int t = i64 ? (int)ew[2 * (E_ + e)] : (int)ew[E_ + e];
            const int pos = atomicAdd(&cur[t], 1);
            csrS[pos] = s * BT;              // pre-scaled for k_att
        }
        return;
    }

    // ---- GEMM path (blocks 1..750) ----
    // Stage W' 34816 B -> LDS (one-time, 2176 x 16B chunks over 512 thr)
    {
        const uint4* wsrc = (const uint4*)Wall;
        uint4*       wdst = (uint4*)smemRaw;
        for (int i = tid; i < 2176; i += 512) wdst[i] = wsrc[i];
    }

    const int wid  = tid >> 6;
    const int lid  = tid & 63;
    const int m    = lid & 15;
    const int q    = lid >> 4;
    const int base = (blockIdx.x - 1) * 128 + wid * 16;

    short8 x0, x1;   // X fragment (B-operand)
    {
        const size_t xoff = (size_t)(base + m) * FIN + q * 8;
        if (flags[0]) {
            const u16* xp = (const u16*)xin + xoff;
            x0 = *reinterpret_cast<const short8*>(xp);
            x1 = *reinterpret_cast<const short8*>(xp + 32);
        } else {
            const float* xp = (const float*)xin + xoff;
            union { short8 v; u16 e[8]; } p0, p1;
#pragma unroll
            for (int i = 0; i < 8; i++) {
                p0.e[i] = f2bf(xp[i]);
                p1.e[i] = f2bf(xp[i + 32]);
            }
            x0 = p0.v;
            x1 = p1.v;
        }
    }

    // per-lane output row: row = bt*1000 + n  ->  ob = n*BT + bt
    const u32 rowm = (u32)(base + m);
    const u32 bt   = rowm / 1000u;
    const u32 n    = rowm - bt * 1000u;
    const u32 obm  = n * BT + bt;

    u16* projBase = projT + (size_t)obm * HF;
    u16* skipBase = skipT + (size_t)obm * HF;

    __syncthreads();   // W' staged

    const char* WL = (const char*)smemRaw;
    const int   fo = q * 256 + m * 16;   // per-lane fragment byte offset

#pragma unroll
    for (int t = 0; t < 16; t++) {
        const short8 b0 = *reinterpret_cast<const short8*>(WL + t * 2048 + fo);
        const short8 b1 = *reinterpret_cast<const short8*>(WL + t * 2048 + 1024 + fo);
        float4v acc = {0.f, 0.f, 0.f, 0.f};
        acc = __builtin_amdgcn_mfma_f32_16x16x32_bf16(b0, x0, acc, 0, 0, 0);
        acc = __builtin_amdgcn_mfma_f32_16x16x32_bf16(b1, x1, acc, 0, 0, 0);

        u16* dst = (t < 8) ? projBase : skipBase;
        const int col = ((t < 8) ? t : (t - 8)) * 16 + q * 4;
        uint2 v;
        v.x = pack2bf(acc[0], acc[1]);
        v.y = pack2bf(acc[2], acc[3]);
        *reinterpret_cast<uint2*>(dst + col) = v;          // 8B aligned store
    }

    {   // score tile: W' rows 256..271 -> sT cols 0..15 (aS | aT)
        const short8 b0 = *reinterpret_cast<const short8*>(WL + 16 * 2048 + fo);
        const short8 b1 = *reinterpret_cast<const short8*>(WL + 16 * 2048 + 1024 + fo);
        float4v acc = {0.f, 0.f, 0.f, 0.f};
        acc = __builtin_amdgcn_mfma_f32_16x16x32_bf16(b0, x0, acc, 0, 0, 0);
        acc = __builtin_amdgcn_mfma_f32_16x16x32_bf16(b1, x1, acc, 0, 0, 0);
        *reinterpret_cast<float4v*>(sT + (size_t)obm * 16 + q * 4) = acc; // 16B
    }
}

// ---------------------------------------------------------------------------
// K2: attention gather, lane-specialized weights. grid (N_, 24), 256 thr.
// Wave -> bt = by*4 + wid. Lane j2: OUTPUT role owns cols 2*j2,2*j2+1
// (h_out = j2>>3); WEIGHT role computes exp for edge-slot (j2>>3), head
// (j2&7) -> 8x less exp/score work; consumers fetch via __shfl.
// No global-max subtraction: softmax is shift-invariant and scores are
// structurally bounded (|s| <~ 15 << 88), so exp cannot overflow.
// ---------------------------------------------------------------------------
__global__ __launch_bounds__(256) void k_att(const u16* __restrict__ projT,
                                             const u16* __restrict__ skipT,
                                             const float* __restrict__ sT,
                                             const int* __restrict__ offs,
                                             const int* __restrict__ csrS,
                                             const int* __restrict__ flags,
                                             void* __restrict__ out)
{
    const int n   = blockIdx.x;
    const int tid = threadIdx.x;
    const int bt  = blockIdx.y * 4 + (tid >> 6);
    const int j2  = tid & 63;
    const int hw  = j2 & 7;     // weight-role head
    const int ho  = j2 >> 3;    // output-role head / weight-role edge slot

    __shared__ int csrL[64];    // holds src*BT

    const float st_w   = sT[((size_t)n * BT + bt) * 16 + 8 + hw];
    const int   sboff  = bt * 16 + hw;          // score addr = csrL*16 + sboff
    const u32   oboff  = (u32)bt * HF + 2 * j2; // proj  addr = csrL*128 + oboff

    float y0 = 0.f, y1 = 0.f, den = 0.f;
    const int e0 = offs[n], e1 = offs[n + 1];

    for (int base = e0; base < e1; base += 64) {
        const int cnt = min(64, e1 - base);
        __syncthreads();
        if (tid < cnt) csrL[tid] = csrS[base + tid];
        __syncthreads();

        for (int i0 = 0; i0 < cnt; i0 += 8) {
            // weight role: one exp per lane
            const int eIdx = i0 + ho;
            const int sBTw = csrL[(eIdx < cnt) ? eIdx : 0];
            const float ss = sT[(size_t)sBTw * 16 + sboff];
            float sc = ss + st_w;
            sc = fmaxf(sc, 0.2f * sc);                  // leaky_relu(0.2)
            const float wm = (eIdx < cnt) ? __expf(sc) : 0.f;

            // accumulate 8 edges; weight for (edge k, head ho) from lane k*8+ho
#pragma unroll
            for (int k = 0; k < 8; k++) {
                const float wk = __shfl(wm, k * 8 + ho, 64);
                const int sBT = csrL[(i0 + k < cnt) ? (i0 + k) : 0];
                const u32 pq = *(const u32*)(projT + (size_t)sBT * HF + oboff);
                float lo, hi;
                unpack2(pq, lo, hi);
                den += wk;
                y0 = fmaf(wk, lo, y0);
                y1 = fmaf(wk, hi, y1);
            }
        }
    }

    const float rden = __builtin_amdgcn_rcpf(den + 1e-16f);
    float sk0, sk1;
    {
        const u32 sq = *(const u32*)(skipT + ((size_t)n * BT + bt) * HF + 2 * j2);
        unpack2(sq, sk0, sk1);
    }
    float o0 = fmaf(y0, rden, sk0);
    float o1 = fmaf(y1, rden, sk1);
    o0 = o0 > 0.f ? o0 : __expf(o0) - 1.0f;             // ELU (bf16-exact enough)
    o1 = o1 > 0.f ? o1 : __expf(o1) - 1.0f;

    const size_t ob = ((size_t)bt * N_ + n) * HF + 2 * j2;
    if (flags[0]) {
        ((u32*)out)[ob >> 1] = (u32)f2bf(o0) | ((u32)f2bf(o1) << 16);
    } else {
        *(float2*)((float*)out + ob) = make_float2(o0, o1);
    }
}

// ---------------------------------------------------------------------------
extern "C" void kernel_launch(void* const* d_in, const int* in_sizes, int n_in,
                              void* d_out, int out_size, void* d_ws, size_t ws_size,
                              hipStream_t stream)
{
    const void* x   = d_in[0];
    const u32*  ew  = (const u32*)d_in[1];
    const void* Wp  = d_in[2];
    const void* as_ = d_in[3];
    const void* at_ = d_in[4];
    const void* Ws  = d_in[5];

    float* ws    = (float*)d_ws;
    int*   flags = (int*)(ws + OFF_FLAGS);
    int*   offs  = (int*)(ws + OFF_OFFS);
    int*   csrS  = (int*)(ws + OFF_CSR);
    u16*   Wall  = (u16*)(ws + OFF_WALL);
    float* sT    = ws + OFF_ST;
    u16*   projT = (u16*)(ws + OFF_PROJ);
    u16*   skipT = (u16*)(ws + OFF_SKIP);

    k_prep<<<1, 1024, 0, stream>>>((const u32*)x, ew, Wp, Ws, as_, at_,
                                   flags, Wall);
    k_mfma<<<751, 512, 0, stream>>>(x, Wall, flags, ew,
                                    projT, skipT, sT, offs, csrS);
    k_att <<<dim3(1000, 24), 256, 0, stream>>>(projT, skipT, sT,
                                               offs, csrS, flags, d_out);
}

// Round 3
// 142.006 us; speedup vs baseline: 1.1752x; 1.0509x over previous
//
#include <hip/hip_runtime.h>
#include <math.h>

#define B_   8
#define T_   12
#define BT   96      // B*T
#define N_   1000
#define FIN  64
#define H_   8
#define FOUT 16
#define HF   128     // H*FOUT
#define E_   8000

typedef unsigned short u16;
typedef unsigned int   u32;
typedef __attribute__((ext_vector_type(8))) short  short8;   // 8 bf16 (4 VGPR)
typedef __attribute__((ext_vector_type(4))) float  float4v;  // MFMA acc

__device__ __forceinline__ float bf2f(u16 u) {
    return __uint_as_float(((u32)u) << 16);
}
__device__ __forceinline__ void unpack2(u32 q, float& lo, float& hi) {
    lo = __uint_as_float(q << 16);
    hi = __uint_as_float(q & 0xffff0000u);
}
__device__ __forceinline__ u16 f2bf(float f) {
    u32 x = __float_as_uint(f);
    u32 r = (x + 0x7fffu + ((x >> 16) & 1u)) >> 16;   // RNE
    return (u16)r;
}
__device__ __forceinline__ u32 pack2bf(float lo, float hi) {
    return (u32)f2bf(lo) | ((u32)f2bf(hi) << 16);
}

// Fragment-permuted W' layout: element (row r, col c) of the 272x64 W' lives
// at u16 index (((r>>4)*8 + (c>>5)*4 + ((c>>3)&3))*16 + (r&15))*8 + (c&7).
// => tile t / lane (m,q) reads its two 16B MFMA fragments at LDS bytes
// t*2048 + q*256 + m*16  and  t*2048 + 1024 + q*256 + m*16: a wave's 64
// lanes cover 64 consecutive 16B chunks -> conflict-free ds_read_b128.
__device__ __forceinline__ int wpos(int r, int c) {
    return (((r >> 4) * 8 + (c >> 5) * 4 + ((c >> 3) & 3)) * 16 + (r & 15)) * 8
           + (c & 7);
}

// ---------------------------------------------------------------------------
// Workspace carve (float-element offsets).
// ---------------------------------------------------------------------------
#define OFF_FLAGS   0         // 4 ints
#define OFF_OFFS    264       // 1004 ints
#define OFF_CSR     1268      // 8000 ints (stores src*BT, grouped by target)
#define OFF_ST      17972     // 1536000 sT fp32 [n][bt][16]
#define OFF_PROJ    1553972   // projT bf16 [n][bt][128] = 12.288M u16
#define OFF_SKIP    7697972   // skipT bf16 [n][bt][128]

// ---------------------------------------------------------------------------
// K1: MFMA GEMM  C[96000 x 272] = X[96000 x 64] . W'^T.
// k_prep is GONE: each GEMM block self-probes the x dtype
// (__syncthreads_count ballot on the same 256-word criterion) and builds W'
// (proj | skip | aS-fold | aT-fold) directly in LDS from the raw L2-hot
// weights (~1 us/block, hidden under the early-issued X global load).
// Block 0 builds the CSR + writes flags for k_att; GEMM = blocks 1..750.
// ---------------------------------------------------------------------------
__global__ __launch_bounds__(512) void k_mfma(const void* __restrict__ xin,
                                              const void* __restrict__ Wp,
                                              const void* __restrict__ Ws,
                                              const void* __restrict__ as_,
                                              const void* __restrict__ at_,
                                              const u32* __restrict__ ew,
                                              int* __restrict__ flags,
                                              u16* __restrict__ projT,
                                              u16* __restrict__ skipT,
                                              float* __restrict__ sT,
                                              int* __restrict__ offs,
                                              int* __restrict__ csrS)
{
    __shared__ __align__(16) unsigned char smemRaw[34816];

    const int tid = threadIdx.x;

    if (blockIdx.x == 0) {
        // ---- probes + CSR build (1 block, overlapped with GEMM blocks) ----
        int* cnt = (int*)smemRaw;          // [1000]
        int* cur = cnt + 1000;             // [1000]
        int* sc  = cur + 1000;             // [512]

        int pred = 0;
        if (tid < 256) {   // bf16-vs-fp32 probe on x
            const u32 w = ((const u32*)xin)[tid];
            const int e = (int)((w >> 7) & 0xFFu);
            pred = (e == 0 || (e >= 95 && e <= 140)) ? 1 : 0;
        }
        const int votes = __syncthreads_count(pred);
        u32 o = 0;
        for (int i = 2 * tid + 1; i < 16000; i += 1024) o |= ew[i];
        const u32 orAll = (u32)__syncthreads_or((int)o);
        const bool i64 = (orAll == 0u);
        if (tid == 0) {
            flags[0] = (votes >= 160) ? 1 : 0;
            flags[1] = i64 ? 1 : 0;
        }

        for (int i = tid; i < N_; i += 512) cnt[i] = 0;
        __syncthreads();
        for (int e = tid; e < E_; e += 512) {
            const int t = i64 ? (int)ew[2 * (E_ + e)] : (int)ew[E_ + e];
            atomicAdd(&cnt[t], 1);
        }
        __syncthreads();
        // blocked exclusive scan: thread t owns idx 2t, 2t+1 (t < 500)
        int s0 = 0, s1 = 0, tot = 0;
        if (tid < 500) {
            s0 = cnt[2 * tid];
            s1 = cnt[2 * tid + 1];
            tot = s0 + s1;
        }
        sc[tid] = tot;
        __syncthreads();
        for (int d = 1; d < 512; d <<= 1) {
            int v = (tid >= d) ? sc[tid - d] : 0;
            __syncthreads();
            sc[tid] += v;
            __syncthreads();
        }
        int excl = (tid ? sc[tid - 1] : 0);
        if (tid < 500) {
            offs[2 * tid]     = excl;
            offs[2 * tid + 1] = excl + s0;
            cur[2 * tid]      = excl;
            cur[2 * tid + 1]  = excl + s0;
        }
        if (tid == 0) offs[N_] = E_;
        __syncthreads();
        for (int e = tid; e < E_; e += 512) {
            const int s = i64 ? (int)ew[2 * e] : (int)ew[e];
            const int t = i64 ? (int)ew[2 * (E_ + e)] : (int)ew[E_ + e];
            const int pos = atomicAdd(&cur[t], 1);
            csrS[pos] = s * BT;              // pre-scaled for k_att
        }
        return;
    }

    // ---- GEMM path (blocks 1..750) ----
    // self-probe x dtype (identical criterion to block 0; deterministic)
    int pred = 0;
    if (tid < 256) {
        const u32 w = ((const u32*)xin)[tid];
        const int e = (int)((w >> 7) & 0xFFu);
        pred = (e == 0 || (e >= 95 && e <= 140)) ? 1 : 0;
    }
    const int votes = __syncthreads_count(pred);
    const bool bf = votes >= 160;

    const int wid  = tid >> 6;
    const int lid  = tid & 63;
    const int m    = lid & 15;
    const int q    = lid >> 4;
    const int base = (blockIdx.x - 1) * 128 + wid * 16;

    // issue X load early; W' build below hides its latency
    short8 x0, x1;   // X fragment (B-operand)
    {
        const size_t xoff = (size_t)(base + m) * FIN + q * 8;
        if (bf) {
            const u16* xp = (const u16*)xin + xoff;
            x0 = *reinterpret_cast<const short8*>(xp);
            x1 = *reinterpret_cast<const short8*>(xp + 32);
        } else {
            const float* xp = (const float*)xin + xoff;
            union { short8 v; u16 e[8]; } p0, p1;
#pragma unroll
            for (int i = 0; i < 8; i++) {
                p0.e[i] = f2bf(xp[i]);
                p1.e[i] = f2bf(xp[i + 32]);
            }
            x0 = p0.v;
            x1 = p1.v;
        }
    }

    // build W' (permuted) in LDS from raw weights
    u16* wl = (u16*)smemRaw;
    for (int i = tid; i < HF * FIN; i += 512) {
        const int r = i >> 6, c = i & 63;
        const float wp = bf ? bf2f(((const u16*)Wp)[i]) : ((const float*)Wp)[i];
        const float wv = bf ? bf2f(((const u16*)Ws)[i]) : ((const float*)Ws)[i];
        wl[wpos(r, c)]       = f2bf(wp);
        wl[wpos(128 + r, c)] = f2bf(wv);
    }
    __syncthreads();
    {   // a-fold: thread -> (h, k); writes tile-16 region (disjoint from reads)
        const int h = tid >> 6, k = tid & 63;
        float s1 = 0.f, s2 = 0.f;
#pragma unroll
        for (int f = 0; f < FOUT; f++) {
            const float w  = bf2f(wl[wpos(h * FOUT + f, k)]);
            const float a1 = bf ? bf2f(((const u16*)as_)[h * FOUT + f])
                                : ((const float*)as_)[h * FOUT + f];
            const float a2 = bf ? bf2f(((const u16*)at_)[h * FOUT + f])
                                : ((const float*)at_)[h * FOUT + f];
            s1 = fmaf(a1, w, s1);
            s2 = fmaf(a2, w, s2);
        }
        wl[wpos(256 + h, k)] = f2bf(s1);   // aS rows
        wl[wpos(264 + h, k)] = f2bf(s2);   // aT rows
    }

    // per-lane output row: row = bt*1000 + n  ->  ob = n*BT + bt
    const u32 rowm = (u32)(base + m);
    const u32 bt   = rowm / 1000u;
    const u32 n    = rowm - bt * 1000u;
    const u32 obm  = n * BT + bt;

    u16* projBase = projT + (size_t)obm * HF;
    u16* skipBase = skipT + (size_t)obm * HF;

    __syncthreads();   // W' complete

    const char* WL = (const char*)smemRaw;
    const int   fo = q * 256 + m * 16;   // per-lane fragment byte offset

#pragma unroll
    for (int t = 0; t < 16; t++) {
        const short8 b0 = *reinterpret_cast<const short8*>(WL + t * 2048 + fo);
        const short8 b1 = *reinterpret_cast<const short8*>(WL + t * 2048 + 1024 + fo);
        float4v acc = {0.f, 0.f, 0.f, 0.f};
        acc = __builtin_amdgcn_mfma_f32_16x16x32_bf16(b0, x0, acc, 0, 0, 0);
        acc = __builtin_amdgcn_mfma_f32_16x16x32_bf16(b1, x1, acc, 0, 0, 0);

        u16* dst = (t < 8) ? projBase : skipBase;
        const int col = ((t < 8) ? t : (t - 8)) * 16 + q * 4;
        uint2 v;
        v.x = pack2bf(acc[0], acc[1]);
        v.y = pack2bf(acc[2], acc[3]);
        *reinterpret_cast<uint2*>(dst + col) = v;          // 8B aligned store
    }

    {   // score tile: W' rows 256..271 -> sT cols 0..15 (aS | aT)
        const short8 b0 = *reinterpret_cast<const short8*>(WL + 16 * 2048 + fo);
        const short8 b1 = *reinterpret_cast<const short8*>(WL + 16 * 2048 + 1024 + fo);
        float4v acc = {0.f, 0.f, 0.f, 0.f};
        acc = __builtin_amdgcn_mfma_f32_16x16x32_bf16(b0, x0, acc, 0, 0, 0);
        acc = __builtin_amdgcn_mfma_f32_16x16x32_bf16(b1, x1, acc, 0, 0, 0);
        *reinterpret_cast<float4v*>(sT + (size_t)obm * 16 + q * 4) = acc; // 16B
    }
}

// ---------------------------------------------------------------------------
// K2: attention gather, 2 bt per wave. grid (N_, 12), 256 thr.
// Wave -> bt pair {2*btp, 2*btp+1}, btp = by*4 + wid. proj rows for
// (src,bt) and (src,bt+1) are contiguous -> one uint2 (4 bf16 cols) gather
// per lane covers both bt: halves wave count AND gather instructions.
// Roles: OUTPUT lane j2 owns bt half (j2>>5), cols 4*(j2&31)..+3 (one head);
// WEIGHT lane j2 computes exp for edge-slot (j2>>4), bt half ((j2>>3)&1),
// head (j2&7) -> 4 edges per pass; consumers fetch via __shfl.
// No global-max subtraction: softmax is shift-invariant and scores are
// structurally bounded (|s| <~ 15 << 88), so exp cannot overflow.
// ---------------------------------------------------------------------------
__global__ __launch_bounds__(256) void k_att(const u16* __restrict__ projT,
                                             const u16* __restrict__ skipT,
                                             const float* __restrict__ sT,
                                             const int* __restrict__ offs,
                                             const int* __restrict__ csrS,
                                             const int* __restrict__ flags,
                                             void* __restrict__ out)
{
    const int n   = blockIdx.x;
    const int tid = threadIdx.x;
    const int btp = blockIdx.y * 4 + (tid >> 6);   // 0..47
    const int bt0 = btp * 2;
    const int j2  = tid & 63;
    // weight role
    const int sw  = j2 >> 4;          // edge slot 0..3
    const int bw  = (j2 >> 3) & 1;    // bt half
    const int hw  = j2 & 7;           // head
    // output role
    const int bo  = j2 >> 5;          // bt half
    const int lo5 = j2 & 31;
    const int c0  = lo5 * 4;          // cols c0..c0+3 (single head)
    const int ho  = lo5 >> 2;         // head of those cols

    __shared__ int csrL[64];          // holds src*BT

    const int bt_w = bt0 + bw;
    const int bt_o = bt0 + bo;
    const float st_w  = sT[((size_t)n * BT + bt_w) * 16 + 8 + hw];
    const int   sboff = bt_w * 16 + hw;           // score addr = csrL*16 + sboff
    const u32   oboff = (u32)bt_o * HF + c0;      // proj  addr = csrL*128 + oboff

    float y0 = 0.f, y1 = 0.f, y2 = 0.f, y3 = 0.f, den = 0.f;
    const int e0 = offs[n], e1 = offs[n + 1];

    for (int base = e0; base < e1; base += 64) {
        const int cnt = min(64, e1 - base);
        __syncthreads();
        if (tid < cnt) csrL[tid] = csrS[base + tid];
        __syncthreads();

        for (int i0 = 0; i0 < cnt; i0 += 4) {
            // weight role: one exp per lane (4 edges x 2 bt x 8 heads)
            const int eIdx = i0 + sw;
            const int sBTw = csrL[(eIdx < cnt) ? eIdx : 0];
            const float ss = sT[(size_t)sBTw * 16 + sboff];
            float scv = ss + st_w;
            scv = fmaxf(scv, 0.2f * scv);               // leaky_relu(0.2)
            const float wm = (eIdx < cnt) ? __expf(scv) : 0.f;

            // accumulate 4 edges; weight for (edge k, bt bo, head ho)
#pragma unroll
            for (int k = 0; k < 4; k++) {
                const float wk = __shfl(wm, k * 16 + bo * 8 + ho, 64);
                const int sBT = csrL[(i0 + k < cnt) ? (i0 + k) : 0];
                const uint2 pq = *(const uint2*)(projT + (size_t)sBT * HF + oboff);
                float f0, f1, f2, f3;
                unpack2(pq.x, f0, f1);
                unpack2(pq.y, f2, f3);
                den += wk;
                y0 = fmaf(wk, f0, y0);
                y1 = fmaf(wk, f1, y1);
                y2 = fmaf(wk, f2, y2);
                y3 = fmaf(wk, f3, y3);
            }
        }
    }

    const float rden = __builtin_amdgcn_rcpf(den + 1e-16f);
    float sk0, sk1, sk2, sk3;
    {
        const uint2 sq = *(const uint2*)(skipT + ((size_t)n * BT + bt_o) * HF + c0);
        unpack2(sq.x, sk0, sk1);
        unpack2(sq.y, sk2, sk3);
    }
    float o0 = fmaf(y0, rden, sk0);
    float o1 = fmaf(y1, rden, sk1);
    float o2 = fmaf(y2, rden, sk2);
    float o3 = fmaf(y3, rden, sk3);
    o0 = o0 > 0.f ? o0 : __expf(o0) - 1.0f;             // ELU (bf16-exact enough)
    o1 = o1 > 0.f ? o1 : __expf(o1) - 1.0f;
    o2 = o2 > 0.f ? o2 : __expf(o2) - 1.0f;
    o3 = o3 > 0.f ? o3 : __expf(o3) - 1.0f;

    const size_t ob = ((size_t)bt_o * N_ + n) * HF + c0;
    if (flags[0]) {
        uint2 v;
        v.x = pack2bf(o0, o1);
        v.y = pack2bf(o2, o3);
        *reinterpret_cast<uint2*>((u16*)out + ob) = v;
    } else {
        *reinterpret_cast<float4*>((float*)out + ob) = make_float4(o0, o1, o2, o3);
    }
}

// ---------------------------------------------------------------------------
extern "C" void kernel_launch(void* const* d_in, const int* in_sizes, int n_in,
                              void* d_out, int out_size, void* d_ws, size_t ws_size,
                              hipStream_t stream)
{
    const void* x   = d_in[0];
    const u32*  ew  = (const u32*)d_in[1];
    const void* Wp  = d_in[2];
    const void* as_ = d_in[3];
    const void* at_ = d_in[4];
    const void* Ws  = d_in[5];

    float* ws    = (float*)d_ws;
    int*   flags = (int*)(ws + OFF_FLAGS);
    int*   offs  = (int*)(ws + OFF_OFFS);
    int*   csrS  = (int*)(ws + OFF_CSR);
    float* sT    = ws + OFF_ST;
    u16*   projT = (u16*)(ws + OFF_PROJ);
    u16*   skipT = (u16*)(ws + OFF_SKIP);

    k_mfma<<<751, 512, 0, stream>>>(x, Wp, Ws, as_, at_, ew, flags,
                                    projT, skipT, sT, offs, csrS);
    k_att <<<dim3(1000, 12), 256, 0, stream>>>(projT, skipT, sT,
                                               offs, csrS, flags, d_out);
}

// Round 4
// 130.288 us; speedup vs baseline: 1.2809x; 1.0899x over previous
//
#include <hip/hip_runtime.h>
#include <math.h>

#define B_   8
#define T_   12
#define BT   96      // B*T
#define N_   1000
#define FIN  64
#define H_   8
#define FOUT 16
#define HF   128     // H*FOUT
#define E_   8000

typedef unsigned short u16;
typedef unsigned int   u32;
typedef __attribute__((ext_vector_type(8))) short  short8;   // 8 bf16 (4 VGPR)
typedef __attribute__((ext_vector_type(4))) float  float4v;  // MFMA acc

__device__ __forceinline__ float bf2f(u16 u) {
    return __uint_as_float(((u32)u) << 16);
}
__device__ __forceinline__ void unpack2(u32 q, float& lo, float& hi) {
    lo = __uint_as_float(q << 16);
    hi = __uint_as_float(q & 0xffff0000u);
}
__device__ __forceinline__ u16 f2bf(float f) {
    u32 x = __float_as_uint(f);
    u32 r = (x + 0x7fffu + ((x >> 16) & 1u)) >> 16;   // RNE
    return (u16)r;
}
__device__ __forceinline__ u32 pack2bf(float lo, float hi) {
    return (u32)f2bf(lo) | ((u32)f2bf(hi) << 16);
}

// Fragment-permuted W' layout: element (row r, col c) of the 272x64 W' lives
// at u16 index (((r>>4)*8 + (c>>5)*4 + ((c>>3)&3))*16 + (r&15))*8 + (c&7).
// => tile t / lane (m,q) reads its two 16B MFMA fragments at LDS bytes
// t*2048 + q*256 + m*16  and  t*2048 + 1024 + q*256 + m*16: a wave's 64
// lanes cover 64 consecutive 16B chunks -> conflict-free ds_read_b128.
// For c0 = 8-aligned col, wpos(r,c0)..wpos(r,c0)+7 are consecutive u16
// (16B-aligned) -> whole-fragment 16B LDS writes during the build.
__device__ __forceinline__ int wpos(int r, int c) {
    return (((r >> 4) * 8 + (c >> 5) * 4 + ((c >> 3) & 3)) * 16 + (r & 15)) * 8
           + (c & 7);
}

// ---------------------------------------------------------------------------
// Workspace carve (float-element offsets).
// ---------------------------------------------------------------------------
#define OFF_FLAGS   0         // 4 ints
#define OFF_OFFS    264       // 1004 ints
#define OFF_CSR     1268      // 8000 ints (stores src*BT, grouped by target)
#define OFF_ST      17972     // 1536000 sT fp32 [n][bt][16]
#define OFF_PROJ    1553972   // projT bf16 [n][bt][128] = 12.288M u16
#define OFF_SKIP    7697972   // skipT bf16 [n][bt][128]

// ---------------------------------------------------------------------------
// K1: MFMA GEMM  C[96000 x 272] = X[96000 x 64] . W'^T.
// Each GEMM block self-probes the x dtype and builds W' (proj | skip |
// aS-fold | aT-fold) directly in LDS from the raw L2-hot weights.
// bf16 path: the build is a pure 16B-copy (bf2f->f2bf RNE is identity);
// fp32 path: float4-pair loads + packed 16B ds_writes.
// Block 0 builds the CSR + writes flags for k_att; GEMM = blocks 1..750.
// ---------------------------------------------------------------------------
__global__ __launch_bounds__(512) void k_mfma(const void* __restrict__ xin,
                                              const void* __restrict__ Wp,
                                              const void* __restrict__ Ws,
                                              const void* __restrict__ as_,
                                              const void* __restrict__ at_,
                                              const u32* __restrict__ ew,
                                              int* __restrict__ flags,
                                              u16* __restrict__ projT,
                                              u16* __restrict__ skipT,
                                              float* __restrict__ sT,
                                              int* __restrict__ offs,
                                              int* __restrict__ csrS)
{
    __shared__ __align__(16) unsigned char smemRaw[34816];

    const int tid = threadIdx.x;

    if (blockIdx.x == 0) {
        // ---- probes + CSR build (1 block, overlapped with GEMM blocks) ----
        int* cnt = (int*)smemRaw;          // [1000]
        int* cur = cnt + 1000;             // [1000]
        int* sc  = cur + 1000;             // [512]

        int pred = 0;
        if (tid < 256) {   // bf16-vs-fp32 probe on x
            const u32 w = ((const u32*)xin)[tid];
            const int e = (int)((w >> 7) & 0xFFu);
            pred = (e == 0 || (e >= 95 && e <= 140)) ? 1 : 0;
        }
        const int votes = __syncthreads_count(pred);
        u32 o = 0;
        for (int i = 2 * tid + 1; i < 16000; i += 1024) o |= ew[i];
        const u32 orAll = (u32)__syncthreads_or((int)o);
        const bool i64 = (orAll == 0u);
        if (tid == 0) {
            flags[0] = (votes >= 160) ? 1 : 0;
            flags[1] = i64 ? 1 : 0;
        }

        for (int i = tid; i < N_; i += 512) cnt[i] = 0;
        __syncthreads();
        for (int e = tid; e < E_; e += 512) {
            const int t = i64 ? (int)ew[2 * (E_ + e)] : (int)ew[E_ + e];
            atomicAdd(&cnt[t], 1);
        }
        __syncthreads();
        // blocked exclusive scan: thread t owns idx 2t, 2t+1 (t < 500)
        int s0 = 0, s1 = 0, tot = 0;
        if (tid < 500) {
            s0 = cnt[2 * tid];
            s1 = cnt[2 * tid + 1];
            tot = s0 + s1;
        }
        sc[tid] = tot;
        __syncthreads();
        for (int d = 1; d < 512; d <<= 1) {
            int v = (tid >= d) ? sc[tid - d] : 0;
            __syncthreads();
            sc[tid] += v;
            __syncthreads();
        }
        int excl = (tid ? sc[tid - 1] : 0);
        if (tid < 500) {
            offs[2 * tid]     = excl;
            offs[2 * tid + 1] = excl + s0;
            cur[2 * tid]      = excl;
            cur[2 * tid + 1]  = excl + s0;
        }
        if (tid == 0) offs[N_] = E_;
        __syncthreads();
        for (int e = tid; e < E_; e += 512) {
            const int s = i64 ? (int)ew[2 * e] : (int)ew[e];
            const int t = i64 ? (int)ew[2 * (E_ + e)] : (int)ew[E_ + e];
            const int pos = atomicAdd(&cur[t], 1);
            csrS[pos] = s * BT;              // pre-scaled for k_att
        }
        return;
    }

    // ---- GEMM path (blocks 1..750) ----
    // self-probe x dtype (identical criterion to block 0; deterministic)
    int pred = 0;
    if (tid < 256) {
        const u32 w = ((const u32*)xin)[tid];
        const int e = (int)((w >> 7) & 0xFFu);
        pred = (e == 0 || (e >= 95 && e <= 140)) ? 1 : 0;
    }
    const int votes = __syncthreads_count(pred);
    const bool bf = votes >= 160;

    const int wid  = tid >> 6;
    const int lid  = tid & 63;
    const int m    = lid & 15;
    const int q    = lid >> 4;
    const int base = (blockIdx.x - 1) * 128 + wid * 16;

    // issue X load early; W' build below hides its latency
    short8 x0, x1;   // X fragment (B-operand)
    {
        const size_t xoff = (size_t)(base + m) * FIN + q * 8;
        if (bf) {
            const u16* xp = (const u16*)xin + xoff;
            x0 = *reinterpret_cast<const short8*>(xp);
            x1 = *reinterpret_cast<const short8*>(xp + 32);
        } else {
            const float* xp = (const float*)xin + xoff;
            union { short8 v; u16 e[8]; } p0, p1;
#pragma unroll
            for (int i = 0; i < 8; i++) {
                p0.e[i] = f2bf(xp[i]);
                p1.e[i] = f2bf(xp[i + 32]);
            }
            x0 = p0.v;
            x1 = p1.v;
        }
    }

    // build W' (permuted) in LDS — vectorized: 8 cols per iter
    u16* wl = (u16*)smemRaw;
    if (bf) {
        const short8* wpv = (const short8*)Wp;
        const short8* wsv = (const short8*)Ws;
        for (int i8 = tid; i8 < (HF * FIN) / 8; i8 += 512) {
            const int r = i8 >> 3, c0 = (i8 & 7) * 8;
            *reinterpret_cast<short8*>(wl + wpos(r, c0))       = wpv[i8];
            *reinterpret_cast<short8*>(wl + wpos(128 + r, c0)) = wsv[i8];
        }
    } else {
        const float4* wpv = (const float4*)Wp;
        const float4* wsv = (const float4*)Ws;
        for (int i8 = tid; i8 < (HF * FIN) / 8; i8 += 512) {
            const int r = i8 >> 3, c0 = (i8 & 7) * 8;
            float4 va = wpv[i8 * 2], vb = wpv[i8 * 2 + 1];
            union { short8 v; u16 e[8]; } p;
            p.e[0] = f2bf(va.x); p.e[1] = f2bf(va.y);
            p.e[2] = f2bf(va.z); p.e[3] = f2bf(va.w);
            p.e[4] = f2bf(vb.x); p.e[5] = f2bf(vb.y);
            p.e[6] = f2bf(vb.z); p.e[7] = f2bf(vb.w);
            *reinterpret_cast<short8*>(wl + wpos(r, c0)) = p.v;
            va = wsv[i8 * 2]; vb = wsv[i8 * 2 + 1];
            p.e[0] = f2bf(va.x); p.e[1] = f2bf(va.y);
            p.e[2] = f2bf(va.z); p.e[3] = f2bf(va.w);
            p.e[4] = f2bf(vb.x); p.e[5] = f2bf(vb.y);
            p.e[6] = f2bf(vb.z); p.e[7] = f2bf(vb.w);
            *reinterpret_cast<short8*>(wl + wpos(128 + r, c0)) = p.v;
        }
    }
    __syncthreads();
    {   // a-fold: thread -> (h, k); writes tile-16 region (disjoint from reads)
        const int h = tid >> 6, k = tid & 63;
        float s1 = 0.f, s2 = 0.f;
#pragma unroll
        for (int f = 0; f < FOUT; f++) {
            const float w  = bf2f(wl[wpos(h * FOUT + f, k)]);
            const float a1 = bf ? bf2f(((const u16*)as_)[h * FOUT + f])
                                : ((const float*)as_)[h * FOUT + f];
            const float a2 = bf ? bf2f(((const u16*)at_)[h * FOUT + f])
                                : ((const float*)at_)[h * FOUT + f];
            s1 = fmaf(a1, w, s1);
            s2 = fmaf(a2, w, s2);
        }
        wl[wpos(256 + h, k)] = f2bf(s1);   // aS rows
        wl[wpos(264 + h, k)] = f2bf(s2);   // aT rows
    }

    // per-lane output row: row = bt*1000 + n  ->  ob = n*BT + bt
    const u32 rowm = (u32)(base + m);
    const u32 bt   = rowm / 1000u;
    const u32 n    = rowm - bt * 1000u;
    const u32 obm  = n * BT + bt;

    u16* projBase = projT + (size_t)obm * HF;
    u16* skipBase = skipT + (size_t)obm * HF;

    __syncthreads();   // W' complete

    const char* WL = (const char*)smemRaw;
    const int   fo = q * 256 + m * 16;   // per-lane fragment byte offset

#pragma unroll
    for (int t = 0; t < 16; t++) {
        const short8 b0 = *reinterpret_cast<const short8*>(WL + t * 2048 + fo);
        const short8 b1 = *reinterpret_cast<const short8*>(WL + t * 2048 + 1024 + fo);
        float4v acc = {0.f, 0.f, 0.f, 0.f};
        acc = __builtin_amdgcn_mfma_f32_16x16x32_bf16(b0, x0, acc, 0, 0, 0);
        acc = __builtin_amdgcn_mfma_f32_16x16x32_bf16(b1, x1, acc, 0, 0, 0);

        u16* dst = (t < 8) ? projBase : skipBase;
        const int col = ((t < 8) ? t : (t - 8)) * 16 + q * 4;
        uint2 v;
        v.x = pack2bf(acc[0], acc[1]);
        v.y = pack2bf(acc[2], acc[3]);
        *reinterpret_cast<uint2*>(dst + col) = v;          // 8B aligned store
    }

    {   // score tile: W' rows 256..271 -> sT cols 0..15 (aS | aT)
        const short8 b0 = *reinterpret_cast<const short8*>(WL + 16 * 2048 + fo);
        const short8 b1 = *reinterpret_cast<const short8*>(WL + 16 * 2048 + 1024 + fo);
        float4v acc = {0.f, 0.f, 0.f, 0.f};
        acc = __builtin_amdgcn_mfma_f32_16x16x32_bf16(b0, x0, acc, 0, 0, 0);
        acc = __builtin_amdgcn_mfma_f32_16x16x32_bf16(b1, x1, acc, 0, 0, 0);
        *reinterpret_cast<float4v*>(sT + (size_t)obm * 16 + q * 4) = acc; // 16B
    }
}

// ---------------------------------------------------------------------------
// K2: attention gather, 2 bt per wave, XCD-pinned bt-slices. grid 12000.
// Block decode: b = (wgid&7)*1500 + (wgid>>3); by = b/1000; n = b%1000.
// Assuming round-robin wgid->XCD (wgid%8), each bt-slice `by` (projT
// working set [*, by*8..by*8+8) = 2 MB + ~0.5 MB sT) lands on <=2 XCDs and
// each XCD holds <=1.5 slices (~3.5 MB < 4 MB L2) -> the deg~8x proj
// re-reads become L2 hits instead of L3-latency gathers.
// Roles per wave (covers bt pair): OUTPUT lane j2 owns bt half (j2>>5),
// cols 4*(j2&31)..+3; WEIGHT lane j2 computes exp for edge-slot (j2>>4),
// bt half ((j2>>3)&1), head (j2&7); consumers fetch via __shfl.
// No global-max subtraction: softmax is shift-invariant and scores are
// structurally bounded (|s| <~ 15 << 88), so exp cannot overflow.
// ---------------------------------------------------------------------------
__global__ __launch_bounds__(256) void k_att(const u16* __restrict__ projT,
                                             const u16* __restrict__ skipT,
                                             const float* __restrict__ sT,
                                             const int* __restrict__ offs,
                                             const int* __restrict__ csrS,
                                             const int* __restrict__ flags,
                                             void* __restrict__ out)
{
    const int wg  = blockIdx.x;                    // 0..11999
    const int b   = (wg & 7) * 1500 + (wg >> 3);   // XCD-pinned remap
    const int by  = b / 1000;                      // bt-slice 0..11
    const int n   = b - by * 1000;
    const int tid = threadIdx.x;
    const int btp = by * 4 + (tid >> 6);           // 0..47
    const int bt0 = btp * 2;
    const int j2  = tid & 63;
    // weight role
    const int sw  = j2 >> 4;          // edge slot 0..3
    const int bw  = (j2 >> 3) & 1;    // bt half
    const int hw  = j2 & 7;           // head
    // output role
    const int bo  = j2 >> 5;          // bt half
    const int lo5 = j2 & 31;
    const int c0  = lo5 * 4;          // cols c0..c0+3 (single head)
    const int ho  = lo5 >> 2;         // head of those cols

    __shared__ int csrL[64];          // holds src*BT

    const int bt_w = bt0 + bw;
    const int bt_o = bt0 + bo;
    const float st_w  = sT[((size_t)n * BT + bt_w) * 16 + 8 + hw];
    const int   sboff = bt_w * 16 + hw;           // score addr = csrL*16 + sboff
    const u32   oboff = (u32)bt_o * HF + c0;      // proj  addr = csrL*128 + oboff

    float y0 = 0.f, y1 = 0.f, y2 = 0.f, y3 = 0.f, den = 0.f;
    const int e0 = offs[n], e1 = offs[n + 1];

    for (int base = e0; base < e1; base += 64) {
        const int cnt = min(64, e1 - base);
        __syncthreads();
        if (tid < cnt) csrL[tid] = csrS[base + tid];
        __syncthreads();

        for (int i0 = 0; i0 < cnt; i0 += 4) {
            // weight role: one exp per lane (4 edges x 2 bt x 8 heads)
            const int eIdx = i0 + sw;
            const int sBTw = csrL[(eIdx < cnt) ? eIdx : 0];
            const float ss = sT[(size_t)sBTw * 16 + sboff];
            float scv = ss + st_w;
            scv = fmaxf(scv, 0.2f * scv);               // leaky_relu(0.2)
            const float wm = (eIdx < cnt) ? __expf(scv) : 0.f;

            // accumulate 4 edges; weight for (edge k, bt bo, head ho)
#pragma unroll
            for (int k = 0; k < 4; k++) {
                const float wk = __shfl(wm, k * 16 + bo * 8 + ho, 64);
                const int sBT = csrL[(i0 + k < cnt) ? (i0 + k) : 0];
                const uint2 pq = *(const uint2*)(projT + (size_t)sBT * HF + oboff);
                float f0, f1, f2, f3;
                unpack2(pq.x, f0, f1);
                unpack2(pq.y, f2, f3);
                den += wk;
                y0 = fmaf(wk, f0, y0);
                y1 = fmaf(wk, f1, y1);
                y2 = fmaf(wk, f2, y2);
                y3 = fmaf(wk, f3, y3);
            }
        }
    }

    const float rden = __builtin_amdgcn_rcpf(den + 1e-16f);
    float sk0, sk1, sk2, sk3;
    {
        const uint2 sq = *(const uint2*)(skipT + ((size_t)n * BT + bt_o) * HF + c0);
        unpack2(sq.x, sk0, sk1);
        unpack2(sq.y, sk2, sk3);
    }
    float o0 = fmaf(y0, rden, sk0);
    float o1 = fmaf(y1, rden, sk1);
    float o2 = fmaf(y2, rden, sk2);
    float o3 = fmaf(y3, rden, sk3);
    o0 = o0 > 0.f ? o0 : __expf(o0) - 1.0f;             // ELU (bf16-exact enough)
    o1 = o1 > 0.f ? o1 : __expf(o1) - 1.0f;
    o2 = o2 > 0.f ? o2 : __expf(o2) - 1.0f;
    o3 = o3 > 0.f ? o3 : __expf(o3) - 1.0f;

    const size_t ob = ((size_t)bt_o * N_ + n) * HF + c0;
    if (flags[0]) {
        uint2 v;
        v.x = pack2bf(o0, o1);
        v.y = pack2bf(o2, o3);
        *reinterpret_cast<uint2*>((u16*)out + ob) = v;
    } else {
        *reinterpret_cast<float4*>((float*)out + ob) = make_float4(o0, o1, o2, o3);
    }
}

// ---------------------------------------------------------------------------
extern "C" void kernel_launch(void* const* d_in, const int* in_sizes, int n_in,
                              void* d_out, int out_size, void* d_ws, size_t ws_size,
                              hipStream_t stream)
{
    const void* x   = d_in[0];
    const u32*  ew  = (const u32*)d_in[1];
    const void* Wp  = d_in[2];
    const void* as_ = d_in[3];
    const void* at_ = d_in[4];
    const void* Ws  = d_in[5];

    float* ws    = (float*)d_ws;
    int*   flags = (int*)(ws + OFF_FLAGS);
    int*   offs  = (int*)(ws + OFF_OFFS);
    int*   csrS  = (int*)(ws + OFF_CSR);
    float* sT    = ws + OFF_ST;
    u16*   projT = (u16*)(ws + OFF_PROJ);
    u16*   skipT = (u16*)(ws + OFF_SKIP);

    k_mfma<<<751, 512, 0, stream>>>(x, Wp, Ws, as_, at_, ew, flags,
                                    projT, skipT, sT, offs, csrS);
    k_att <<<12000, 256, 0, stream>>>(projT, skipT, sT,
                                      offs, csrS, flags, d_out);
}